// Round 5
// baseline (198.080 us; speedup 1.0000x reference)
//
#include <hip/hip_runtime.h>

#define BN_EPS 1e-3f

typedef __attribute__((ext_vector_type(8))) short bf16x8;
typedef __attribute__((ext_vector_type(4))) float f32x4;

__device__ inline unsigned short f2b(float f) {
    unsigned int u = __float_as_uint(f);
    unsigned int r = (u + 0x7fffu + ((u >> 16) & 1u)) >> 16;
    return (unsigned short)r;
}
__device__ inline float b2f(unsigned short h) {
    return __uint_as_float(((unsigned int)h) << 16);
}

// ---------------------------------------------------------------------------
// k_prep: Bt[n][k] = bf16 of (n<256 ? Wi[k][n] : Wr[k][n-256])   [320,256]
//         Wst[n][k] = bf16 of Ws[k][n]                            [144,64]
// ---------------------------------------------------------------------------
__global__ void k_prep(const float* __restrict__ Wi, const float* __restrict__ Wr,
                       const float* __restrict__ Ws,
                       unsigned short* __restrict__ Bt, unsigned short* __restrict__ Wst) {
    int t = blockIdx.x * 256 + threadIdx.x;
    if (t < 320 * 256) {
        int n = t >> 8, k = t & 255;
        float v = (n < 256) ? Wi[k * 256 + n] : Wr[k * 64 + (n - 256)];
        Bt[t] = f2b(v);
    } else {
        int t2 = t - 320 * 256;
        if (t2 < 144 * 64) {
            int n = t2 >> 6, k = t2 & 63;
            Wst[t2] = f2b(Ws[k * 144 + n]);
        }
    }
}

// ---------------------------------------------------------------------------
// k_xiw: per block, 128 consecutive pixels (no halo). grid=512 -> exactly
// 2 blocks/CU resident, zero tail. 512 threads (8 waves, 2M x 4N split).
//   xi = bf16(x@Wi + bi)  -> stored DIRECTLY from accumulators to xi_g.
//   r  = relu(BN(x@Wr))   -> RS LDS (aliases dead X region).
//   w  = bf16(r@Ws^T + bs)-> w_g.
// LDS (u16): X [128][264] = 67,584 B; RS [128][72] aliases X after GEMM.
// 3 barriers/block. __launch_bounds__(512,4) caps VGPR at 128 -> 16 waves/CU.
// ---------------------------------------------------------------------------
#define AXIP 264
#define ASMN (128 * AXIP)            // 33792 u16 = 67,584 B
#define ARSP 72

__global__ __launch_bounds__(512, 4) void k_xiw(
    const float* __restrict__ x, const unsigned short* __restrict__ Bt,
    const unsigned short* __restrict__ Wst,
    const float* __restrict__ bi, const float* __restrict__ br,
    const float* __restrict__ gamma, const float* __restrict__ beta,
    const float* __restrict__ mean, const float* __restrict__ var,
    const float* __restrict__ bs,
    unsigned short* __restrict__ xi_g, unsigned short* __restrict__ w_g)
{
    __shared__ __attribute__((aligned(16))) unsigned short sm[ASMN];
    const int tid = threadIdx.x;
    const long long px0 = (long long)blockIdx.x * 128;

    const int wv = tid >> 6;          // 0..7
    const int lane = tid & 63;
    const int col = lane & 15;
    const int quad = lane >> 4;
    const int mh = wv >> 2;           // 0..1: m-half (rows mh*64..mh*64+63)
    const int nq = wv & 3;            // 0..3: j-tiles nq*5..nq*5+4

    // ---- stage x[128][256] f32 -> X LDS bf16 (fully coalesced) ----
#pragma unroll
    for (int it = 0; it < 8; ++it) {
        const int flat = it * 512 + tid;       // chunk of 8 floats
        const int px = flat >> 5;
        const int cho = (flat & 31) * 8;
        const float* src = x + (px0 + px) * 256 + cho;
        float4 v0 = *(const float4*)&src[0];
        float4 v1 = *(const float4*)&src[4];
        int4 pk;
        pk.x = (int)((unsigned)f2b(v0.x) | ((unsigned)f2b(v0.y) << 16));
        pk.y = (int)((unsigned)f2b(v0.z) | ((unsigned)f2b(v0.w) << 16));
        pk.z = (int)((unsigned)f2b(v1.x) | ((unsigned)f2b(v1.y) << 16));
        pk.w = (int)((unsigned)f2b(v1.z) | ((unsigned)f2b(v1.w) << 16));
        *(int4*)&sm[px * AXIP + cho] = pk;
    }
    __syncthreads();

    // ---- main GEMM: wave = 4 m-tiles (mh half) x 5 j-tiles, K=256 ----
    f32x4 acc[5][4];
#pragma unroll
    for (int jj = 0; jj < 5; ++jj)
#pragma unroll
        for (int m = 0; m < 4; ++m) acc[jj][m] = (f32x4){0.f, 0.f, 0.f, 0.f};

#pragma unroll
    for (int kc = 0; kc < 8; ++kc) {
        const int kb = kc * 32 + quad * 8;
        bf16x8 a[4];
#pragma unroll
        for (int m = 0; m < 4; ++m)
            a[m] = *(const bf16x8*)&sm[(mh * 64 + m * 16 + col) * AXIP + kb];
#pragma unroll
        for (int jj = 0; jj < 5; ++jj) {
            const int j = nq * 5 + jj;
            bf16x8 b = *(const bf16x8*)&Bt[(j * 16 + col) * 256 + kb];
#pragma unroll
            for (int m = 0; m < 4; ++m)
                acc[jj][m] = __builtin_amdgcn_mfma_f32_16x16x32_bf16(a[m], b, acc[jj][m], 0, 0, 0);
        }
    }
    __syncthreads();   // all X reads done; X region is now dead (RS aliases it)

    // ---- epilogue: xi -> direct global stores; r -> RS LDS (alias X) ----
#pragma unroll
    for (int jj = 0; jj < 5; ++jj) {
        const int j = nq * 5 + jj;
        if (j < 16) {
            const int n = j * 16 + col;
            const float bv = bi[n];
#pragma unroll
            for (int m = 0; m < 4; ++m) {
                const long long pxb = px0 + mh * 64 + m * 16 + quad * 4;
#pragma unroll
                for (int rg = 0; rg < 4; ++rg)
                    xi_g[(pxb + rg) * 256 + n] = f2b(acc[jj][m][rg] + bv);
            }
        } else {
            const int d = (j - 16) * 16 + col;
            const float sc = gamma[d] * rsqrtf(var[d] + BN_EPS);
            const float bb2 = (br[d] - mean[d]) * sc + beta[d];
#pragma unroll
            for (int m = 0; m < 4; ++m) {
                const int rowb = mh * 64 + m * 16 + quad * 4;
#pragma unroll
                for (int rg = 0; rg < 4; ++rg) {
                    const float v = acc[jj][m][rg] * sc + bb2;
                    sm[(rowb + rg) * ARSP + d] = f2b(fmaxf(v, 0.f));
                }
            }
        }
    }
    __syncthreads();   // RS complete

    // ---- w-GEMM: wave wv -> m-tile wv (16 px); N=144 (9 j), K=64 ----
    f32x4 wa[9];
#pragma unroll
    for (int j = 0; j < 9; ++j) wa[j] = (f32x4){0.f, 0.f, 0.f, 0.f};
#pragma unroll
    for (int kc = 0; kc < 2; ++kc) {
        const int kb = kc * 32 + quad * 8;
        bf16x8 ra = *(const bf16x8*)&sm[(wv * 16 + col) * ARSP + kb];
#pragma unroll
        for (int j = 0; j < 9; ++j) {
            bf16x8 wb = *(const bf16x8*)&Wst[(j * 16 + col) * 64 + kb];
            wa[j] = __builtin_amdgcn_mfma_f32_16x16x32_bf16(ra, wb, wa[j], 0, 0, 0);
        }
    }
#pragma unroll
    for (int j = 0; j < 9; ++j) {
        const int n = j * 16 + col;
        const float bv = bs[n];
        const long long pxb = px0 + wv * 16 + quad * 4;
#pragma unroll
        for (int rg = 0; rg < 4; ++rg)
            w_g[(pxb + rg) * 144 + n] = f2b(wa[j][rg] + bv);
    }
}

// ---------------------------------------------------------------------------
// k_gather: one block = 8x8 output tile (halo 10x10 = 100 px).
// 512 threads (8 waves). Stage xi halo + w tile -> ONE barrier -> gather.
// LDS (u16): XI [100][264] | WL [64][144] = 71,232 B -> 2 blocks/CU.
// ---------------------------------------------------------------------------
#define GXIP 264
#define GWL_OFF (100 * GXIP)            // 26400 u16
#define GSMN (GWL_OFF + 64 * 144)       // 35616 u16 = 71,232 B

__global__ __launch_bounds__(512, 4) void k_gather(
    const unsigned short* __restrict__ xi_g, const unsigned short* __restrict__ w_g,
    float* __restrict__ out)
{
    __shared__ __attribute__((aligned(16))) unsigned short sm[GSMN];
    const int tid = threadIdx.x;
    // bijective XCD swizzle (1024 blocks, 1024 % 8 == 0)
    const int b = blockIdx.x;
    const int bx = (b & 7) * 128 + (b >> 3);
    const int w0 = (bx & 15) * 8;
    const int h0 = ((bx >> 4) & 15) * 8;
    const int bb = bx >> 8;

    // ---- stage XI halo: 100 px x 256 ch bf16 = 3200 chunks of 16B ----
#pragma unroll
    for (int it = 0; it < 7; ++it) {
        const int flat = it * 512 + tid;
        if (flat < 3200) {
            const int px = flat >> 5;
            const int cho = (flat & 31) * 8;
            const int hr = px / 10, hc = px - hr * 10;
            const int gh = h0 - 1 + hr, gw = w0 - 1 + hc;
            int4 v;
            if (((unsigned)gh < 128u) && ((unsigned)gw < 128u)) {
                const long long pxg = ((long long)(bb * 128 + gh)) * 128 + gw;
                v = *(const int4*)&xi_g[pxg * 256 + cho];
            } else {
                v = (int4){0, 0, 0, 0};
            }
            *(int4*)&sm[px * GXIP + cho] = v;
        }
    }
    // ---- stage WL: 64 px x 144 = 1152 chunks of 16B ----
#pragma unroll
    for (int it = 0; it < 3; ++it) {
        const int flat = it * 512 + tid;
        if (flat < 1152) {
            const int px = flat / 18;
            const int cho = (flat - px * 18) * 8;
            const long long pxg =
                ((long long)(bb * 128 + h0 + (px >> 3))) * 128 + (w0 + (px & 7));
            int4 v = *(const int4*)&w_g[pxg * 144 + cho];
            *(int4*)&sm[GWL_OFF + px * 144 + cho] = v;
        }
    }
    __syncthreads();

    // ---- gather: g = tid&15 (coalesced 1KB out per 16-lane group) ----
    {
        const int g = tid & 15;
        const int pb = tid >> 4;               // 0..31

        const int idx0 = g * 144;
        const int kp0  = idx0 >> 8;
        const int c0   = idx0 & 255;           // multiple of 16
        int len1 = 256 - c0; if (len1 > 144) len1 = 144;
        const int kp1  = kp0 + 1;
        const int koff0 = (kp0 / 3) * 10 + (kp0 % 3);
        const int koff1 = (kp1 <= 8) ? ((kp1 / 3) * 10 + (kp1 % 3)) : 0;

#pragma unroll
        for (int jj = 0; jj < 2; ++jj) {
            const int p = pb + 32 * jj;        // interior px 0..63
            const int phb = (p >> 3) * 10 + (p & 7);
            const int base0 = (phb + koff0) * GXIP + c0;
            const int base1 = (phb + koff1) * GXIP;

            float wf[9];
#pragma unroll
            for (int kk = 0; kk < 9; ++kk)
                wf[kk] = b2f(sm[GWL_OFF + p * 144 + g * 9 + kk]);

            float res[16];
            {
                int4 xv[9];
#pragma unroll
                for (int i = 0; i < 9; ++i) {
                    const int e = i * 8;
                    const int addr = (e < len1) ? (base0 + e) : (base1 + (e - len1));
                    xv[i] = *(const int4*)&sm[addr];
                }
#pragma unroll
                for (int f2 = 0; f2 < 8; ++f2) {
                    float a = 0.f;
#pragma unroll
                    for (int kk = 0; kk < 9; ++kk) {
                        const int e = f2 * 9 + kk;
                        const int word = ((const int*)&xv[e >> 3])[(e >> 1) & 3];
                        const unsigned short u = (e & 1) ? (unsigned short)(((unsigned)word) >> 16)
                                                         : (unsigned short)(word & 0xffff);
                        a += wf[kk] * b2f(u);
                    }
                    res[f2] = a;
                }
            }
            {
                int4 xv[9];
#pragma unroll
                for (int i = 9; i < 18; ++i) {
                    const int e = i * 8;
                    const int addr = (e < len1) ? (base0 + e) : (base1 + (e - len1));
                    xv[i - 9] = *(const int4*)&sm[addr];
                }
#pragma unroll
                for (int f2 = 8; f2 < 16; ++f2) {
                    float a = 0.f;
#pragma unroll
                    for (int kk = 0; kk < 9; ++kk) {
                        const int e = f2 * 9 + kk;
                        const int i = (e >> 3) - 9;
                        const int word = ((const int*)&xv[i])[(e >> 1) & 3];
                        const unsigned short u = (e & 1) ? (unsigned short)(((unsigned)word) >> 16)
                                                         : (unsigned short)(word & 0xffff);
                        a += wf[kk] * b2f(u);
                    }
                    res[f2] = a;
                }
            }

            const long long orow =
                (((long long)(bb * 128 + h0 + (p >> 3))) * 128 + (w0 + (p & 7))) * 256 + g * 16;
#pragma unroll
            for (int q = 0; q < 4; ++q) {
                float4 o = {res[q * 4 + 0], res[q * 4 + 1], res[q * 4 + 2], res[q * 4 + 3]};
                *(float4*)&out[orow + q * 4] = o;
            }
        }
    }
}

// ---------------------------------------------------------------------------
extern "C" void kernel_launch(void* const* d_in, const int* in_sizes, int n_in,
                              void* d_out, int out_size, void* d_ws, size_t ws_size,
                              hipStream_t stream) {
    const float* x     = (const float*)d_in[0];
    const float* Wr    = (const float*)d_in[1];
    const float* br    = (const float*)d_in[2];
    const float* gamma = (const float*)d_in[3];
    const float* beta  = (const float*)d_in[4];
    const float* mean  = (const float*)d_in[5];
    const float* var   = (const float*)d_in[6];
    const float* Ws    = (const float*)d_in[7];
    const float* bs    = (const float*)d_in[8];
    const float* Wi    = (const float*)d_in[9];
    const float* bi    = (const float*)d_in[10];
    float* out = (float*)d_out;

    unsigned char* ws = (unsigned char*)d_ws;
    unsigned short* Bt   = (unsigned short*)(ws + 0);         // 163,840 B
    unsigned short* Wst  = (unsigned short*)(ws + 163840);    //  18,432 B
    unsigned short* xi_g = (unsigned short*)(ws + 182272);    // 65536*256*2 = 33,554,432 B
    unsigned short* w_g  = (unsigned short*)(ws + 33736704);  // 65536*144*2 = 18,874,368 B
    // total workspace use: 52,611,072 B

    k_prep<<<dim3(356), dim3(256), 0, stream>>>(Wi, Wr, Ws, Bt, Wst);
    k_xiw<<<dim3(512), dim3(512), 0, stream>>>(
        x, Bt, Wst, bi, br, gamma, beta, mean, var, bs, xi_g, w_g);
    k_gather<<<dim3(1024), dim3(512), 0, stream>>>(xi_g, w_g, out);
}

// Round 6
// 188.144 us; speedup vs baseline: 1.0528x; 1.0528x over previous
//
#include <hip/hip_runtime.h>

#define BN_EPS 1e-3f

typedef __attribute__((ext_vector_type(8))) short bf16x8;
typedef __attribute__((ext_vector_type(4))) float f32x4;

__device__ inline unsigned short f2b(float f) {
    unsigned int u = __float_as_uint(f);
    unsigned int r = (u + 0x7fffu + ((u >> 16) & 1u)) >> 16;
    return (unsigned short)r;
}
__device__ inline float b2f(unsigned short h) {
    return __uint_as_float(((unsigned int)h) << 16);
}

// ---------------------------------------------------------------------------
// k_prep: Bt[n][k] = bf16 of (n<256 ? Wi[k][n] : Wr[k][n-256])   [320,256]
//         Wst[n][k] = bf16 of Ws[k][n]                            [144,64]
// ---------------------------------------------------------------------------
__global__ void k_prep(const float* __restrict__ Wi, const float* __restrict__ Wr,
                       const float* __restrict__ Ws,
                       unsigned short* __restrict__ Bt, unsigned short* __restrict__ Wst) {
    int t = blockIdx.x * 256 + threadIdx.x;
    if (t < 320 * 256) {
        int n = t >> 8, k = t & 255;
        float v = (n < 256) ? Wi[k * 256 + n] : Wr[k * 64 + (n - 256)];
        Bt[t] = f2b(v);
    } else {
        int t2 = t - 320 * 256;
        if (t2 < 144 * 64) {
            int n = t2 >> 6, k = t2 & 63;
            Wst[t2] = f2b(Ws[k * 144 + n]);
        }
    }
}

// ---------------------------------------------------------------------------
// k_xiw v3 (no-spill): per block, 64 consecutive pixels. grid=1024.
// 512 threads (8 waves). Wave wv: xi n-tiles {wv, wv+8} over all 4 m-tiles;
// waves 0-3 additionally r n-tile 16+wv. Per-wave live state:
//   acc 8-12 f32x4 (32-48) + a[4] (32) + 2-3 B frags (8-12) ~= 90 regs < 128.
//   xi stored directly from accumulators; r -> RS (separate LDS region).
// LDS (u16): X [64][264] = 33,792 B + RS [64][72] = 9,216 B = 43,008 B.
// 2 barriers/block.
// ---------------------------------------------------------------------------
#define AXIP 264
#define ARS_OFF (64 * AXIP)           // 16896 u16
#define ARSP 72
#define ASMN (ARS_OFF + 64 * ARSP)    // 21504 u16 = 43,008 B

__global__ __launch_bounds__(512, 4) void k_xiw(
    const float* __restrict__ x, const unsigned short* __restrict__ Bt,
    const unsigned short* __restrict__ Wst,
    const float* __restrict__ bi, const float* __restrict__ br,
    const float* __restrict__ gamma, const float* __restrict__ beta,
    const float* __restrict__ mean, const float* __restrict__ var,
    const float* __restrict__ bs,
    unsigned short* __restrict__ xi_g, unsigned short* __restrict__ w_g)
{
    __shared__ __attribute__((aligned(16))) unsigned short sm[ASMN];
    const int tid = threadIdx.x;
    const long long px0 = (long long)blockIdx.x * 64;

    const int wv = tid >> 6;          // 0..7
    const int lane = tid & 63;
    const int col = lane & 15;
    const int quad = lane >> 4;

    // ---- stage x[64][256] f32 -> X LDS bf16 (coalesced, 4 iters) ----
#pragma unroll
    for (int it = 0; it < 4; ++it) {
        const int flat = it * 512 + tid;       // chunk of 8 floats
        const int px = flat >> 5;
        const int cho = (flat & 31) * 8;
        const float* src = x + (px0 + px) * 256 + cho;
        float4 v0 = *(const float4*)&src[0];
        float4 v1 = *(const float4*)&src[4];
        int4 pk;
        pk.x = (int)((unsigned)f2b(v0.x) | ((unsigned)f2b(v0.y) << 16));
        pk.y = (int)((unsigned)f2b(v0.z) | ((unsigned)f2b(v0.w) << 16));
        pk.z = (int)((unsigned)f2b(v1.x) | ((unsigned)f2b(v1.y) << 16));
        pk.w = (int)((unsigned)f2b(v1.z) | ((unsigned)f2b(v1.w) << 16));
        *(int4*)&sm[px * AXIP + cho] = pk;
    }
    __syncthreads();

    // ---- main GEMM: wave = 4 m-tiles x {j1=wv, j2=wv+8, (wv<4) jr=16+wv} ----
    f32x4 acc1[4], acc2[4], accr[4];
#pragma unroll
    for (int m = 0; m < 4; ++m) {
        acc1[m] = (f32x4){0.f, 0.f, 0.f, 0.f};
        acc2[m] = acc1[m];
        accr[m] = acc1[m];
    }

    const unsigned short* pB1 = &Bt[(wv * 16 + col) * 256];
    const unsigned short* pB2 = &Bt[((wv + 8) * 16 + col) * 256];
    const unsigned short* pBr = &Bt[(256 + (wv & 3) * 16 + col) * 256];

#pragma unroll
    for (int kc = 0; kc < 8; ++kc) {
        const int kb = kc * 32 + quad * 8;
        bf16x8 a0 = *(const bf16x8*)&sm[(0 * 16 + col) * AXIP + kb];
        bf16x8 a1 = *(const bf16x8*)&sm[(1 * 16 + col) * AXIP + kb];
        bf16x8 a2 = *(const bf16x8*)&sm[(2 * 16 + col) * AXIP + kb];
        bf16x8 a3 = *(const bf16x8*)&sm[(3 * 16 + col) * AXIP + kb];
        bf16x8 b1 = *(const bf16x8*)&pB1[kb];
        bf16x8 b2 = *(const bf16x8*)&pB2[kb];
        acc1[0] = __builtin_amdgcn_mfma_f32_16x16x32_bf16(a0, b1, acc1[0], 0, 0, 0);
        acc1[1] = __builtin_amdgcn_mfma_f32_16x16x32_bf16(a1, b1, acc1[1], 0, 0, 0);
        acc1[2] = __builtin_amdgcn_mfma_f32_16x16x32_bf16(a2, b1, acc1[2], 0, 0, 0);
        acc1[3] = __builtin_amdgcn_mfma_f32_16x16x32_bf16(a3, b1, acc1[3], 0, 0, 0);
        acc2[0] = __builtin_amdgcn_mfma_f32_16x16x32_bf16(a0, b2, acc2[0], 0, 0, 0);
        acc2[1] = __builtin_amdgcn_mfma_f32_16x16x32_bf16(a1, b2, acc2[1], 0, 0, 0);
        acc2[2] = __builtin_amdgcn_mfma_f32_16x16x32_bf16(a2, b2, acc2[2], 0, 0, 0);
        acc2[3] = __builtin_amdgcn_mfma_f32_16x16x32_bf16(a3, b2, acc2[3], 0, 0, 0);
        if (wv < 4) {
            bf16x8 br_ = *(const bf16x8*)&pBr[kb];
            accr[0] = __builtin_amdgcn_mfma_f32_16x16x32_bf16(a0, br_, accr[0], 0, 0, 0);
            accr[1] = __builtin_amdgcn_mfma_f32_16x16x32_bf16(a1, br_, accr[1], 0, 0, 0);
            accr[2] = __builtin_amdgcn_mfma_f32_16x16x32_bf16(a2, br_, accr[2], 0, 0, 0);
            accr[3] = __builtin_amdgcn_mfma_f32_16x16x32_bf16(a3, br_, accr[3], 0, 0, 0);
        }
    }

    // ---- epilogue: xi -> direct global stores; r -> RS (separate region,
    //      no barrier needed vs X reads) ----
    {
        const int n1 = wv * 16 + col;
        const int n2 = n1 + 128;
        const float bv1 = bi[n1];
        const float bv2 = bi[n2];
#pragma unroll
        for (int m = 0; m < 4; ++m) {
            const long long pxb = px0 + m * 16 + quad * 4;
#pragma unroll
            for (int rg = 0; rg < 4; ++rg) {
                xi_g[(pxb + rg) * 256 + n1] = f2b(acc1[m][rg] + bv1);
                xi_g[(pxb + rg) * 256 + n2] = f2b(acc2[m][rg] + bv2);
            }
        }
        if (wv < 4) {
            const int d = (wv & 3) * 16 + col;
            const float sc = gamma[d] * rsqrtf(var[d] + BN_EPS);
            const float bb2 = (br[d] - mean[d]) * sc + beta[d];
#pragma unroll
            for (int m = 0; m < 4; ++m) {
                const int rowb = m * 16 + quad * 4;
#pragma unroll
                for (int rg = 0; rg < 4; ++rg) {
                    const float v = accr[m][rg] * sc + bb2;
                    sm[ARS_OFF + (rowb + rg) * ARSP + d] = f2b(fmaxf(v, 0.f));
                }
            }
        }
    }
    __syncthreads();   // RS complete

    // ---- w-GEMM: wave -> (m-tile = wv&3, j-half = wv>>2); N=144, K=64 ----
    {
        const int mt = wv & 3;
        const int jh = wv >> 2;
        const int jb = jh * 5;
        const int njt = 5 - jh;          // jh0: j=0..4, jh1: j=5..8
        const int arow = ARS_OFF + (mt * 16 + col) * ARSP;
        bf16x8 ra0 = *(const bf16x8*)&sm[arow + quad * 8];
        bf16x8 ra1 = *(const bf16x8*)&sm[arow + 32 + quad * 8];

        f32x4 wacc[5];
#pragma unroll
        for (int jj = 0; jj < 5; ++jj) wacc[jj] = (f32x4){0.f, 0.f, 0.f, 0.f};
#pragma unroll
        for (int jj = 0; jj < 5; ++jj) {
            if (jj < njt) {
                const unsigned short* wp = &Wst[((jb + jj) * 16 + col) * 64];
                bf16x8 wb0 = *(const bf16x8*)&wp[quad * 8];
                bf16x8 wb1 = *(const bf16x8*)&wp[32 + quad * 8];
                wacc[jj] = __builtin_amdgcn_mfma_f32_16x16x32_bf16(ra0, wb0, wacc[jj], 0, 0, 0);
                wacc[jj] = __builtin_amdgcn_mfma_f32_16x16x32_bf16(ra1, wb1, wacc[jj], 0, 0, 0);
            }
        }
#pragma unroll
        for (int jj = 0; jj < 5; ++jj) {
            if (jj < njt) {
                const int n = (jb + jj) * 16 + col;
                const float bv = bs[n];
                const long long pxb = px0 + mt * 16 + quad * 4;
#pragma unroll
                for (int rg = 0; rg < 4; ++rg)
                    w_g[(pxb + rg) * 144 + n] = f2b(wacc[jj][rg] + bv);
            }
        }
    }
}

// ---------------------------------------------------------------------------
// k_gather: one block = 8x8 output tile (halo 10x10 = 100 px).
// 512 threads (8 waves). Stage xi halo + w tile -> ONE barrier -> gather.
// LDS (u16): XI [100][264] | WL [64][144] = 71,232 B -> 2 blocks/CU.
// ---------------------------------------------------------------------------
#define GXIP 264
#define GWL_OFF (100 * GXIP)            // 26400 u16
#define GSMN (GWL_OFF + 64 * 144)       // 35616 u16 = 71,232 B

__global__ __launch_bounds__(512, 4) void k_gather(
    const unsigned short* __restrict__ xi_g, const unsigned short* __restrict__ w_g,
    float* __restrict__ out)
{
    __shared__ __attribute__((aligned(16))) unsigned short sm[GSMN];
    const int tid = threadIdx.x;
    // bijective XCD swizzle (1024 blocks, 1024 % 8 == 0)
    const int b = blockIdx.x;
    const int bx = (b & 7) * 128 + (b >> 3);
    const int w0 = (bx & 15) * 8;
    const int h0 = ((bx >> 4) & 15) * 8;
    const int bb = bx >> 8;

    // ---- stage XI halo: 100 px x 256 ch bf16 = 3200 chunks of 16B ----
#pragma unroll
    for (int it = 0; it < 7; ++it) {
        const int flat = it * 512 + tid;
        if (flat < 3200) {
            const int px = flat >> 5;
            const int cho = (flat & 31) * 8;
            const int hr = px / 10, hc = px - hr * 10;
            const int gh = h0 - 1 + hr, gw = w0 - 1 + hc;
            int4 v;
            if (((unsigned)gh < 128u) && ((unsigned)gw < 128u)) {
                const long long pxg = ((long long)(bb * 128 + gh)) * 128 + gw;
                v = *(const int4*)&xi_g[pxg * 256 + cho];
            } else {
                v = (int4){0, 0, 0, 0};
            }
            *(int4*)&sm[px * GXIP + cho] = v;
        }
    }
    // ---- stage WL: 64 px x 144 = 1152 chunks of 16B ----
#pragma unroll
    for (int it = 0; it < 3; ++it) {
        const int flat = it * 512 + tid;
        if (flat < 1152) {
            const int px = flat / 18;
            const int cho = (flat - px * 18) * 8;
            const long long pxg =
                ((long long)(bb * 128 + h0 + (px >> 3))) * 128 + (w0 + (px & 7));
            int4 v = *(const int4*)&w_g[pxg * 144 + cho];
            *(int4*)&sm[GWL_OFF + px * 144 + cho] = v;
        }
    }
    __syncthreads();

    // ---- gather: g = tid&15 (coalesced 1KB out per 16-lane group) ----
    {
        const int g = tid & 15;
        const int pb = tid >> 4;               // 0..31

        const int idx0 = g * 144;
        const int kp0  = idx0 >> 8;
        const int c0   = idx0 & 255;           // multiple of 16
        int len1 = 256 - c0; if (len1 > 144) len1 = 144;
        const int kp1  = kp0 + 1;
        const int koff0 = (kp0 / 3) * 10 + (kp0 % 3);
        const int koff1 = (kp1 <= 8) ? ((kp1 / 3) * 10 + (kp1 % 3)) : 0;

#pragma unroll
        for (int jj = 0; jj < 2; ++jj) {
            const int p = pb + 32 * jj;        // interior px 0..63
            const int phb = (p >> 3) * 10 + (p & 7);
            const int base0 = (phb + koff0) * GXIP + c0;
            const int base1 = (phb + koff1) * GXIP;

            float wf[9];
#pragma unroll
            for (int kk = 0; kk < 9; ++kk)
                wf[kk] = b2f(sm[GWL_OFF + p * 144 + g * 9 + kk]);

            float res[16];
            {
                int4 xv[9];
#pragma unroll
                for (int i = 0; i < 9; ++i) {
                    const int e = i * 8;
                    const int addr = (e < len1) ? (base0 + e) : (base1 + (e - len1));
                    xv[i] = *(const int4*)&sm[addr];
                }
#pragma unroll
                for (int f2 = 0; f2 < 8; ++f2) {
                    float a = 0.f;
#pragma unroll
                    for (int kk = 0; kk < 9; ++kk) {
                        const int e = f2 * 9 + kk;
                        const int word = ((const int*)&xv[e >> 3])[(e >> 1) & 3];
                        const unsigned short u = (e & 1) ? (unsigned short)(((unsigned)word) >> 16)
                                                         : (unsigned short)(word & 0xffff);
                        a += wf[kk] * b2f(u);
                    }
                    res[f2] = a;
                }
            }
            {
                int4 xv[9];
#pragma unroll
                for (int i = 9; i < 18; ++i) {
                    const int e = i * 8;
                    const int addr = (e < len1) ? (base0 + e) : (base1 + (e - len1));
                    xv[i - 9] = *(const int4*)&sm[addr];
                }
#pragma unroll
                for (int f2 = 8; f2 < 16; ++f2) {
                    float a = 0.f;
#pragma unroll
                    for (int kk = 0; kk < 9; ++kk) {
                        const int e = f2 * 9 + kk;
                        const int i = (e >> 3) - 9;
                        const int word = ((const int*)&xv[i])[(e >> 1) & 3];
                        const unsigned short u = (e & 1) ? (unsigned short)(((unsigned)word) >> 16)
                                                         : (unsigned short)(word & 0xffff);
                        a += wf[kk] * b2f(u);
                    }
                    res[f2] = a;
                }
            }

            const long long orow =
                (((long long)(bb * 128 + h0 + (p >> 3))) * 128 + (w0 + (p & 7))) * 256 + g * 16;
#pragma unroll
            for (int q = 0; q < 4; ++q) {
                float4 o = {res[q * 4 + 0], res[q * 4 + 1], res[q * 4 + 2], res[q * 4 + 3]};
                *(float4*)&out[orow + q * 4] = o;
            }
        }
    }
}

// ---------------------------------------------------------------------------
extern "C" void kernel_launch(void* const* d_in, const int* in_sizes, int n_in,
                              void* d_out, int out_size, void* d_ws, size_t ws_size,
                              hipStream_t stream) {
    const float* x     = (const float*)d_in[0];
    const float* Wr    = (const float*)d_in[1];
    const float* br    = (const float*)d_in[2];
    const float* gamma = (const float*)d_in[3];
    const float* beta  = (const float*)d_in[4];
    const float* mean  = (const float*)d_in[5];
    const float* var   = (const float*)d_in[6];
    const float* Ws    = (const float*)d_in[7];
    const float* bs    = (const float*)d_in[8];
    const float* Wi    = (const float*)d_in[9];
    const float* bi    = (const float*)d_in[10];
    float* out = (float*)d_out;

    unsigned char* ws = (unsigned char*)d_ws;
    unsigned short* Bt   = (unsigned short*)(ws + 0);         // 163,840 B
    unsigned short* Wst  = (unsigned short*)(ws + 163840);    //  18,432 B
    unsigned short* xi_g = (unsigned short*)(ws + 182272);    // 65536*256*2 = 33,554,432 B
    unsigned short* w_g  = (unsigned short*)(ws + 33736704);  // 65536*144*2 = 18,874,368 B
    // total workspace use: 52,611,072 B

    k_prep<<<dim3(356), dim3(256), 0, stream>>>(Wi, Wr, Ws, Bt, Wst);
    k_xiw<<<dim3(1024), dim3(512), 0, stream>>>(
        x, Bt, Wst, bi, br, gamma, beta, mean, var, bs, xi_g, w_g);
    k_gather<<<dim3(1024), dim3(512), 0, stream>>>(xi_g, w_g, out);
}

// Round 7
// 171.361 us; speedup vs baseline: 1.1559x; 1.0979x over previous
//
#include <hip/hip_runtime.h>

#define BN_EPS 1e-3f

typedef __attribute__((ext_vector_type(8))) short bf16x8;
typedef __attribute__((ext_vector_type(4))) float f32x4;

__device__ inline unsigned short f2b(float f) {
    unsigned int u = __float_as_uint(f);
    unsigned int r = (u + 0x7fffu + ((u >> 16) & 1u)) >> 16;
    return (unsigned short)r;
}
__device__ inline float b2f(unsigned short h) {
    return __uint_as_float(((unsigned int)h) << 16);
}
// packed RNE f32x2 -> bf16x2 (lo = a, hi = b) — single VALU instruction
__device__ inline unsigned int pk2(float a, float b) {
    unsigned int r;
    asm("v_cvt_pk_bf16_f32 %0, %1, %2" : "=v"(r) : "v"(a), "v"(b));
    return r;
}

// ---------------------------------------------------------------------------
// k_prep: Bt[n][k] = bf16 of (n<256 ? Wi[k][n] : Wr[k][n-256])   [320,256]
//         Wst[n][k] = bf16 of Ws[k][n]                            [144,64]
// ---------------------------------------------------------------------------
__global__ void k_prep(const float* __restrict__ Wi, const float* __restrict__ Wr,
                       const float* __restrict__ Ws,
                       unsigned short* __restrict__ Bt, unsigned short* __restrict__ Wst) {
    int t = blockIdx.x * 256 + threadIdx.x;
    if (t < 320 * 256) {
        int n = t >> 8, k = t & 255;
        float v = (n < 256) ? Wi[k * 256 + n] : Wr[k * 64 + (n - 256)];
        Bt[t] = f2b(v);
    } else {
        int t2 = t - 320 * 256;
        if (t2 < 144 * 64) {
            int n = t2 >> 6, k = t2 & 63;
            Wst[t2] = f2b(Ws[k * 144 + n]);
        }
    }
}

// ---------------------------------------------------------------------------
// k_fused: one block = one 16x8 output tile (halo 18x10 = 180 px).
//   phase 1 (6 chunks of 32 halo rows, in-place LDS):
//       stage x chunk (fp32->bf16 via v_cvt_pk) -> MFMA xi (N=256) + r (N=64)
//       with register-resident B -> epilogue overwrites A rows with xi, r->RS.
//   phase 2: w = r @ Ws^T (+bs) on compacted 128 interior px -> WL.
//   phase 3: verified contiguous-run gather, out fp32.
// LDS (u16): XI 180x264 | RS 180x72 | WL 128x144  = 157,824 B -> 1 block/CU.
// ---------------------------------------------------------------------------
#define XIP 264
#define RS_OFF (180 * XIP)            // 47520
#define RSP 72
#define WL_OFF (RS_OFF + 180 * RSP)   // 60480
#define SMN (WL_OFF + 128 * 144)      // 78912 u16 = 157,824 B

__global__ __launch_bounds__(512, 2) void k_fused(
    const float* __restrict__ x, const unsigned short* __restrict__ Bt,
    const unsigned short* __restrict__ Wst,
    const float* __restrict__ bi, const float* __restrict__ br,
    const float* __restrict__ gamma, const float* __restrict__ beta,
    const float* __restrict__ mean, const float* __restrict__ var,
    const float* __restrict__ bs, float* __restrict__ out)
{
    __shared__ __attribute__((aligned(16))) unsigned short sm[SMN];
    const int tid = threadIdx.x;
    const int bx = blockIdx.x;
    const int w0 = (bx & 7) * 16;
    const int h0 = ((bx >> 3) & 15) * 8;
    const int bb = bx >> 7;

    const int wv = tid >> 6;
    const int lane = tid & 63;
    const int col = lane & 15;
    const int quad = lane >> 4;

    // ---- load per-wave constants & register-resident B fragments ----
    const float bi_v0 = bi[(2 * wv) * 16 + col];
    const float bi_v1 = bi[(2 * wv + 1) * 16 + col];
    const int dcl = (wv & 3) * 16 + col;       // r-column (valid when wv<4)
    const float brd = br[dcl];
    const float md  = mean[dcl];
    const float sc  = gamma[dcl] * rsqrtf(var[dcl] + BN_EPS);
    const float btv = beta[dcl];

    bf16x8 bx0[8], bx1[8], brr[8];
    {
        const unsigned short* p0 = &Bt[((2 * wv) * 16 + col) * 256];
        const unsigned short* p1 = &Bt[((2 * wv + 1) * 16 + col) * 256];
#pragma unroll
        for (int kc = 0; kc < 8; ++kc) {
            bx0[kc] = *(const bf16x8*)&p0[kc * 32 + quad * 8];
            bx1[kc] = *(const bf16x8*)&p1[kc * 32 + quad * 8];
        }
        if (wv < 4) {
            const unsigned short* pr = &Bt[((16 + wv) * 16 + col) * 256];
#pragma unroll
            for (int kc = 0; kc < 8; ++kc)
                brr[kc] = *(const bf16x8*)&pr[kc * 32 + quad * 8];
        }
    }

    // ---- staging helpers (thread covers halo px hp, 16 ch starting (tid&15)*4,
    //      strided by 64 so each global load instruction is 256B-contiguous) ----
    const int chq = (tid & 15) * 4;

    // prologue: stage chunk 0
    float4 vcur[4];
    int hp_cur;
    {
        hp_cur = (tid >> 4);
        int r = hp_cur / 18, cc = hp_cur - r * 18;
        int gh = h0 - 1 + r, gw = w0 - 1 + cc;
        bool ok = (hp_cur < 180) && ((unsigned)gh < 128u) && ((unsigned)gw < 128u);
        if (ok) {
            const float* src = x + (((long long)(bb * 128 + gh)) * 128 + gw) * 256 + chq;
#pragma unroll
            for (int j = 0; j < 4; ++j) vcur[j] = *(const float4*)&src[j * 64];
        } else {
#pragma unroll
            for (int j = 0; j < 4; ++j) vcur[j] = (float4){0.f, 0.f, 0.f, 0.f};
        }
        if (hp_cur < 180) {
#pragma unroll
            for (int j = 0; j < 4; ++j) {
                uint2 pk;
                pk.x = pk2(vcur[j].x, vcur[j].y);
                pk.y = pk2(vcur[j].z, vcur[j].w);
                *(uint2*)&sm[hp_cur * XIP + chq + j * 64] = pk;
            }
        }
    }
    __syncthreads();

    // ---- chunk loop ----
    for (int c = 0; c < 6; ++c) {
        // issue global loads for chunk c+1 (overlap with MFMAs below)
        float4 vn[4];
        int hp_n = 192;
        if (c < 5) {
            hp_n = (c + 1) * 32 + (tid >> 4);
            int r = hp_n / 18, cc = hp_n - r * 18;
            int gh = h0 - 1 + r, gw = w0 - 1 + cc;
            bool ok = (hp_n < 180) && ((unsigned)gh < 128u) && ((unsigned)gw < 128u);
            if (ok) {
                const float* src = x + (((long long)(bb * 128 + gh)) * 128 + gw) * 256 + chq;
#pragma unroll
                for (int j = 0; j < 4; ++j) vn[j] = *(const float4*)&src[j * 64];
            } else {
#pragma unroll
                for (int j = 0; j < 4; ++j) vn[j] = (float4){0.f, 0.f, 0.f, 0.f};
            }
        }

        // MFMA chunk c
        f32x4 a00 = {0.f,0.f,0.f,0.f}, a01 = a00, a10 = a00, a11 = a00;
        f32x4 ar0 = a00, ar1 = a00;
        {
            const int rowA0 = (c * 32 + col) * XIP;
            const int rowA1 = (c * 32 + 16 + col) * XIP;
#pragma unroll
            for (int kc = 0; kc < 8; ++kc) {
                const int kb = kc * 32 + quad * 8;
                bf16x8 a0 = *(const bf16x8*)&sm[rowA0 + kb];
                bf16x8 a1 = *(const bf16x8*)&sm[rowA1 + kb];
                a00 = __builtin_amdgcn_mfma_f32_16x16x32_bf16(a0, bx0[kc], a00, 0, 0, 0);
                a10 = __builtin_amdgcn_mfma_f32_16x16x32_bf16(a1, bx0[kc], a10, 0, 0, 0);
                a01 = __builtin_amdgcn_mfma_f32_16x16x32_bf16(a0, bx1[kc], a01, 0, 0, 0);
                a11 = __builtin_amdgcn_mfma_f32_16x16x32_bf16(a1, bx1[kc], a11, 0, 0, 0);
                if (wv < 4) {
                    ar0 = __builtin_amdgcn_mfma_f32_16x16x32_bf16(a0, brr[kc], ar0, 0, 0, 0);
                    ar1 = __builtin_amdgcn_mfma_f32_16x16x32_bf16(a1, brr[kc], ar1, 0, 0, 0);
                }
            }
        }
        __syncthreads();   // all reads of rows_c done

        // write staged A for chunk c+1 (disjoint rows)
        if (c < 5 && hp_n < 180) {
#pragma unroll
            for (int j = 0; j < 4; ++j) {
                uint2 pk;
                pk.x = pk2(vn[j].x, vn[j].y);
                pk.y = pk2(vn[j].z, vn[j].w);
                *(uint2*)&sm[hp_n * XIP + chq + j * 64] = pk;
            }
        }

        // epilogue chunk c: xi -> XI rows_c, r -> RS rows_c
        {
            const int n0 = (2 * wv) * 16 + col;
            const int n1 = (2 * wv + 1) * 16 + col;
            const int rb = c * 32 + quad * 4;
#pragma unroll
            for (int rg = 0; rg < 4; ++rg) {
                const int r0 = rb + rg, r1 = rb + 16 + rg;
                if (r0 < 180) {
                    const unsigned int u0 = pk2(a00[rg] + bi_v0, a01[rg] + bi_v1);
                    sm[r0 * XIP + n0] = (unsigned short)u0;
                    sm[r0 * XIP + n1] = (unsigned short)(u0 >> 16);
                }
                if (r1 < 180) {
                    const unsigned int u1 = pk2(a10[rg] + bi_v0, a11[rg] + bi_v1);
                    sm[r1 * XIP + n0] = (unsigned short)u1;
                    sm[r1 * XIP + n1] = (unsigned short)(u1 >> 16);
                }
            }
            if (wv < 4) {
#pragma unroll
                for (int rg = 0; rg < 4; ++rg) {
                    const int r0 = rb + rg, r1 = rb + 16 + rg;
                    if (r0 < 180) {
                        float v = (ar0[rg] + brd - md) * sc + btv;
                        sm[RS_OFF + r0 * RSP + dcl] = f2b(fmaxf(v, 0.f));
                    }
                    if (r1 < 180) {
                        float v = (ar1[rg] + brd - md) * sc + btv;
                        sm[RS_OFF + r1 * RSP + dcl] = f2b(fmaxf(v, 0.f));
                    }
                }
            }
        }
        __syncthreads();
    }

    // ---- phase 2: w = r @ Wst^T (+bs) on compacted interior; wave wv -> m-tile wv ----
    {
        f32x4 wacc[9];
#pragma unroll
        for (int j = 0; j < 9; ++j) wacc[j] = (f32x4){0.f, 0.f, 0.f, 0.f};
        // interior px iq = wv*16 + col -> halo row 19 + wv*18 + col
        const int arow = (19 + wv * 18 + col) * RSP;
#pragma unroll
        for (int kc = 0; kc < 2; ++kc) {
            const int kb = kc * 32 + quad * 8;
            bf16x8 ra = *(const bf16x8*)&sm[RS_OFF + arow + kb];
#pragma unroll
            for (int j = 0; j < 9; ++j) {
                bf16x8 wb = *(const bf16x8*)&Wst[(j * 16 + col) * 64 + kb];
                wacc[j] = __builtin_amdgcn_mfma_f32_16x16x32_bf16(ra, wb, wacc[j], 0, 0, 0);
            }
        }
        // store: pair j with j+1 (n-addresses 16 u16 apart in the same row)
        const int prow = wv * 16 + quad * 4;
#pragma unroll
        for (int j = 0; j < 8; j += 2) {
            const int na = j * 16 + col;
            const int nb = na + 16;
            const float bva = bs[na];
            const float bvb = bs[nb];
#pragma unroll
            for (int rg = 0; rg < 4; ++rg) {
                const unsigned int u = pk2(wacc[j][rg] + bva, wacc[j + 1][rg] + bvb);
                sm[WL_OFF + (prow + rg) * 144 + na] = (unsigned short)u;
                sm[WL_OFF + (prow + rg) * 144 + nb] = (unsigned short)(u >> 16);
            }
        }
        {
            const int n = 8 * 16 + col;
            const float bv = bs[n];
#pragma unroll
            for (int rg = 0; rg < 4; ++rg)
                sm[WL_OFF + (prow + rg) * 144 + n] = f2b(wacc[8][rg] + bv);
        }
    }
    __syncthreads();

    // ---- phase 3: gather ----
    {
        const int g = tid & 15;
        const int pb = tid >> 4;               // 0..31

        const int idx0 = g * 144;
        const int kp0  = idx0 >> 8;
        const int c0   = idx0 & 255;           // multiple of 16
        int len1 = 256 - c0; if (len1 > 144) len1 = 144;
        const int kp1  = kp0 + 1;
        const int koff0 = (kp0 / 3) * 18 + (kp0 % 3);
        const int koff1 = (kp1 <= 8) ? ((kp1 / 3) * 18 + (kp1 % 3)) : 0;

#pragma unroll
        for (int jj = 0; jj < 4; ++jj) {
            const int p = pb + 32 * jj;        // interior px 0..127
            const int phb = (p >> 4) * 18 + (p & 15);
            const int base0 = (phb + koff0) * XIP + c0;
            const int base1 = (phb + koff1) * XIP;

            float wf[9];
#pragma unroll
            for (int kk = 0; kk < 9; ++kk)
                wf[kk] = b2f(sm[WL_OFF + p * 144 + g * 9 + kk]);

            float res[16];
            {
                int4 xv[9];
#pragma unroll
                for (int i = 0; i < 9; ++i) {
                    const int e = i * 8;
                    const int addr = (e < len1) ? (base0 + e) : (base1 + (e - len1));
                    xv[i] = *(const int4*)&sm[addr];
                }
#pragma unroll
                for (int f2 = 0; f2 < 8; ++f2) {
                    float a = 0.f;
#pragma unroll
                    for (int kk = 0; kk < 9; ++kk) {
                        const int e = f2 * 9 + kk;
                        const int word = ((const int*)&xv[e >> 3])[(e >> 1) & 3];
                        const unsigned short u = (e & 1) ? (unsigned short)(((unsigned)word) >> 16)
                                                         : (unsigned short)(word & 0xffff);
                        a += wf[kk] * b2f(u);
                    }
                    res[f2] = a;
                }
            }
            {
                int4 xv[9];
#pragma unroll
                for (int i = 9; i < 18; ++i) {
                    const int e = i * 8;
                    const int addr = (e < len1) ? (base0 + e) : (base1 + (e - len1));
                    xv[i - 9] = *(const int4*)&sm[addr];
                }
#pragma unroll
                for (int f2 = 8; f2 < 16; ++f2) {
                    float a = 0.f;
#pragma unroll
                    for (int kk = 0; kk < 9; ++kk) {
                        const int e = f2 * 9 + kk;
                        const int i = (e >> 3) - 9;
                        const int word = ((const int*)&xv[i])[(e >> 1) & 3];
                        const unsigned short u = (e & 1) ? (unsigned short)(((unsigned)word) >> 16)
                                                         : (unsigned short)(word & 0xffff);
                        a += wf[kk] * b2f(u);
                    }
                    res[f2] = a;
                }
            }

            const long long orow =
                (((long long)(bb * 128 + h0 + (p >> 4))) * 128 + (w0 + (p & 15))) * 256 + g * 16;
#pragma unroll
            for (int q = 0; q < 4; ++q) {
                float4 o = {res[q * 4 + 0], res[q * 4 + 1], res[q * 4 + 2], res[q * 4 + 3]};
                *(float4*)&out[orow + q * 4] = o;
            }
        }
    }
}

// ---------------------------------------------------------------------------
extern "C" void kernel_launch(void* const* d_in, const int* in_sizes, int n_in,
                              void* d_out, int out_size, void* d_ws, size_t ws_size,
                              hipStream_t stream) {
    const float* x     = (const float*)d_in[0];
    const float* Wr    = (const float*)d_in[1];
    const float* br    = (const float*)d_in[2];
    const float* gamma = (const float*)d_in[3];
    const float* beta  = (const float*)d_in[4];
    const float* mean  = (const float*)d_in[5];
    const float* var   = (const float*)d_in[6];
    const float* Ws    = (const float*)d_in[7];
    const float* bs    = (const float*)d_in[8];
    const float* Wi    = (const float*)d_in[9];
    const float* bi    = (const float*)d_in[10];
    float* out = (float*)d_out;

    unsigned char* ws = (unsigned char*)d_ws;
    unsigned short* Bt  = (unsigned short*)(ws + 0);        // 320*256*2 = 163,840 B
    unsigned short* Wst = (unsigned short*)(ws + 163840);   // 144*64*2  =  18,432 B

    k_prep<<<dim3(356), dim3(256), 0, stream>>>(Wi, Wr, Ws, Bt, Wst);
    k_fused<<<dim3(512), dim3(512), 0, stream>>>(
        x, Bt, Wst, bi, br, gamma, beta, mean, var, bs, out);
}